// Round 4
// baseline (3652.596 us; speedup 1.0000x reference)
//
#include <hip/hip_runtime.h>
#include <math.h>

#define HIDC 128
#define OUTC 40
#define BN_EPS 1e-5f
#define MAXBUK 784          // >= ceil(100000/128)
#define TILE 8192

// ---------------- bf16 helpers ----------------
__device__ __forceinline__ unsigned short f2bf(float f) {
  union { float f; unsigned u; } v; v.f = f;
  unsigned r = v.u + 0x7fff + ((v.u >> 16) & 1);   // RNE
  return (unsigned short)(r >> 16);
}
__device__ __forceinline__ float bf2f(unsigned short h) {
  union { unsigned u; float f; } v; v.u = ((unsigned)h) << 16;
  return v.f;
}

// ---------------- bucket-CSR build ----------------
// bucket b = dst >> 7 (128 nodes per bucket). pair = src | (dst&127)<<17.

__global__ __launch_bounds__(256) void bin_hist(const int* __restrict__ dst,
                                                int* __restrict__ bucketCount,
                                                int E, int NBUK) {
  __shared__ int h[MAXBUK];
  int t = threadIdx.x;
  for (int i = t; i < NBUK; i += 256) h[i] = 0;
  __syncthreads();
  int idx = blockIdx.x * 256 + t;
  int stride = gridDim.x * 256;
  for (int e = idx; e < E; e += stride) atomicAdd(&h[dst[e] >> 7], 1);
  __syncthreads();
  for (int i = t; i < NBUK; i += 256) if (h[i]) atomicAdd(&bucketCount[i], h[i]);
}

__global__ __launch_bounds__(512) void scan_buckets(const int* __restrict__ bucketCount,
                                                    int* __restrict__ bucketStart,
                                                    int* __restrict__ cursor,
                                                    int NBUK, int E) {
  __shared__ int ssc[512];
  int t = threadIdx.x;
  int c0 = (2 * t < NBUK) ? bucketCount[2 * t] : 0;
  int c1 = (2 * t + 1 < NBUK) ? bucketCount[2 * t + 1] : 0;
  ssc[t] = c0 + c1;
  __syncthreads();
  for (int off = 1; off < 512; off <<= 1) {
    int v = (t >= off) ? ssc[t - off] : 0;
    __syncthreads();
    ssc[t] += v;
    __syncthreads();
  }
  int base = ssc[t] - (c0 + c1);   // exclusive
  if (2 * t < NBUK)     { bucketStart[2 * t] = base;          cursor[2 * t] = base; }
  if (2 * t + 1 < NBUK) { bucketStart[2 * t + 1] = base + c0; cursor[2 * t + 1] = base + c0; }
  if (t == 511) bucketStart[NBUK] = E;
}

__global__ __launch_bounds__(512) void bin_scatter(const int* __restrict__ src,
                                                   const int* __restrict__ dst,
                                                   int* __restrict__ cursor,
                                                   unsigned* __restrict__ pairs,
                                                   int E, int NBUK) {
  __shared__ unsigned ord[TILE];
  __shared__ int hist[MAXBUK], scanS[MAXBUK], gbase[MAXBUK], rank[MAXBUK];
  __shared__ int ssc[512];
  int t = threadIdx.x;
  int tb = blockIdx.x * TILE;
  int nT = min(TILE, E - tb);
  for (int i = t; i < NBUK; i += 512) { hist[i] = 0; rank[i] = 0; }
  __syncthreads();
  for (int i = t; i < nT; i += 512) atomicAdd(&hist[dst[tb + i] >> 7], 1);
  __syncthreads();
  // exclusive scan of hist -> scanS (2 buckets per thread)
  int c0 = (2 * t < NBUK) ? hist[2 * t] : 0;
  int c1 = (2 * t + 1 < NBUK) ? hist[2 * t + 1] : 0;
  ssc[t] = c0 + c1;
  __syncthreads();
  for (int off = 1; off < 512; off <<= 1) {
    int v = (t >= off) ? ssc[t - off] : 0;
    __syncthreads();
    ssc[t] += v;
    __syncthreads();
  }
  int bse = ssc[t] - (c0 + c1);
  if (2 * t < NBUK) scanS[2 * t] = bse;
  if (2 * t + 1 < NBUK) scanS[2 * t + 1] = bse + c0;
  __syncthreads();
  // reserve global ranges (one atomic per nonempty bucket per tile)
  for (int i = t; i < NBUK; i += 512) {
    int c = hist[i];
    if (c) gbase[i] = atomicAdd(&cursor[i], c);
  }
  __syncthreads();
  // bucket-sort the tile into LDS
  for (int i = t; i < nT; i += 512) {
    int d = dst[tb + i], s = src[tb + i];
    int b = d >> 7;
    int pos = scanS[b] + atomicAdd(&rank[b], 1);
    ord[pos] = (unsigned)s | ((unsigned)(d & 127) << 17);
  }
  __syncthreads();
  // coalesced flush: wave per bucket round-robin
  int wid = t >> 6, lane = t & 63;
  for (int b = wid; b < NBUK; b += 8) {
    int c = hist[b];
    if (!c) continue;
    int gb = gbase[b], sb = scanS[b];
    for (int j = lane; j < c; j += 64) pairs[gb + j] = ord[sb + j];
  }
}

// per-bucket degree -> dis (replaces global count_kernel)
__global__ __launch_bounds__(256) void bucket_dis(const unsigned* __restrict__ pairs,
                                                  const int* __restrict__ bucketStart,
                                                  float* __restrict__ dis, int N) {
  __shared__ int cnt[128];
  int b = blockIdx.x, t = threadIdx.x;
  int base = b << 7;
  if (t < 128) cnt[t] = 0;
  __syncthreads();
  int e0 = bucketStart[b], e1 = bucketStart[b + 1];
  for (int e = e0 + t; e < e1; e += 256) atomicAdd(&cnt[pairs[e] >> 17], 1);
  __syncthreads();
  if (t < 128 && base + t < N) dis[base + t] = rsqrtf((float)(cnt[t] + 1));
}

// ---------------- GEMM: [N,128] x [128,128] -> bf16, optional fused BN+ReLU on A ----------------
template<bool BN>
__global__ __launch_bounds__(256) void gemm128(const float* __restrict__ A,
                                               const float* __restrict__ W,
                                               const float* __restrict__ bnsc,
                                               const float* __restrict__ bnsh,
                                               unsigned short* __restrict__ Cbf, int N) {
  __shared__ float Wl[128 * 128];
  __shared__ float Al[64][33];
  __shared__ float scs[128], shs[128];
  int t = threadIdx.x;
  for (int idx = t; idx < 128 * 128; idx += 256) Wl[idx] = W[idx];
  if (BN && t < 128) { scs[t] = bnsc[t]; shs[t] = bnsh[t]; }
  int tr = t >> 5;
  int tc = t & 31;
  int rowBase = blockIdx.x * 64;
  float4 acc[8];
  #pragma unroll
  for (int u = 0; u < 8; ++u) acc[u] = make_float4(0.f, 0.f, 0.f, 0.f);

  for (int kt = 0; kt < 128; kt += 32) {
    __syncthreads();
    #pragma unroll
    for (int u = 0; u < 8; ++u) {
      int id = u * 256 + t;
      int r = id >> 5, col = id & 31;
      int gr = rowBase + r;
      float v = (gr < N) ? A[(size_t)gr * 128 + kt + col] : 0.f;
      if (BN) v = fmaxf(v * scs[kt + col] + shs[kt + col], 0.f);
      Al[r][col] = v;
    }
    __syncthreads();
    #pragma unroll
    for (int kk = 0; kk < 32; ++kk) {
      float4 wv = *(const float4*)&Wl[(kt + kk) * 128 + 4 * tc];
      #pragma unroll
      for (int u = 0; u < 8; ++u) {
        float a = Al[tr * 8 + u][kk];
        acc[u].x += a * wv.x; acc[u].y += a * wv.y;
        acc[u].z += a * wv.z; acc[u].w += a * wv.w;
      }
    }
  }
  #pragma unroll
  for (int u = 0; u < 8; ++u) {
    int gr = rowBase + tr * 8 + u;
    if (gr < N) {
      ushort4 o;
      o.x = f2bf(acc[u].x); o.y = f2bf(acc[u].y);
      o.z = f2bf(acc[u].z); o.w = f2bf(acc[u].w);
      *(ushort4*)&Cbf[(size_t)gr * 128 + 4 * tc] = o;
    }
  }
}

// ---------------- GEMM: [N,128] x [128,40] with fused BN+ReLU on A; writes post-BN A back ----------------
__global__ __launch_bounds__(256) void gemm40(float* __restrict__ A,
                                              const float* __restrict__ W,
                                              const float* __restrict__ bnsc,
                                              const float* __restrict__ bnsh,
                                              unsigned short* __restrict__ Cbf, int N) {
  __shared__ float Wl[128 * OUTC];
  __shared__ float Al[256 * 17];
  __shared__ float scs[128], shs[128];
  int t = threadIdx.x;
  for (int idx = t; idx < 128 * OUTC; idx += 256) Wl[idx] = W[idx];
  if (t < 128) { scs[t] = bnsc[t]; shs[t] = bnsh[t]; }
  int rowBase = blockIdx.x * 256;
  float acc[OUTC];
  #pragma unroll
  for (int c = 0; c < OUTC; ++c) acc[c] = 0.f;

  for (int kt = 0; kt < 128; kt += 16) {
    __syncthreads();
    #pragma unroll
    for (int u = 0; u < 16; ++u) {
      int id = u * 256 + t;
      int r = id >> 4, col = id & 15;
      int gr = rowBase + r;
      if (gr < N) {
        float v = A[(size_t)gr * 128 + kt + col];
        v = fmaxf(v * scs[kt + col] + shs[kt + col], 0.f);
        Al[r * 17 + col] = v;
        A[(size_t)gr * 128 + kt + col] = v;   // h output (post-BN+ReLU)
      } else {
        Al[r * 17 + col] = 0.f;
      }
    }
    __syncthreads();
    #pragma unroll
    for (int kk = 0; kk < 16; ++kk) {
      float a = Al[t * 17 + kk];
      const float* wr = &Wl[(kt + kk) * OUTC];
      #pragma unroll
      for (int c = 0; c < OUTC; ++c) acc[c] += a * wr[c];
    }
  }
  int gr = rowBase + t;
  if (gr < N) {
    unsigned short* cr = Cbf + (size_t)gr * OUTC;
    #pragma unroll
    for (int c4 = 0; c4 < OUTC; c4 += 4) {
      ushort4 o;
      o.x = f2bf(acc[c4]); o.y = f2bf(acc[c4 + 1]);
      o.z = f2bf(acc[c4 + 2]); o.w = f2bf(acc[c4 + 3]);
      *(ushort4*)&cr[c4] = o;
    }
  }
}

// ---------------- bucket aggregation (128 ch): LDS accumulator, 16 edge streams ----------------
__global__ __launch_bounds__(512) void agg128b(const unsigned short* __restrict__ hb,
                                               const float* __restrict__ dis,
                                               const int* __restrict__ bucketStart,
                                               const unsigned* __restrict__ pairs,
                                               const float* __restrict__ bias,
                                               float* __restrict__ outF, int N) {
  __shared__ float acc[128 * 128];   // 64 KB [node][ch]
  __shared__ float disl[128];
  int b = blockIdx.x;
  int base = b << 7;
  int nNodes = min(128, N - base);
  int t = threadIdx.x;
  for (int i = t; i < 128 * 128; i += 512) acc[i] = 0.f;
  if (t < 128) disl[t] = (t < nNodes) ? dis[base + t] : 0.f;
  __syncthreads();
  int e0 = bucketStart[b], e1 = bucketStart[b + 1];
  int q = t & 31;       // stride-32 channel ownership: ch = q + 32k -> bank q (conflict-free)
  int g = t >> 5;       // 16 concurrent edge streams
  for (int e = e0 + g; e < e1; e += 16) {
    unsigned p = pairs[e];
    int s = p & 0x1FFFF;
    int dl = p >> 17;
    float w = dis[s] * disl[dl];
    const unsigned short* row = hb + (size_t)s * 128;
    float* arow = acc + dl * 128;
    #pragma unroll
    for (int k = 0; k < 4; ++k) {
      float v = bf2f(row[q + 32 * k]);
      atomicAdd(&arow[q + 32 * k], v * w);   // ds_add_f32
    }
  }
  __syncthreads();
  // epilogue: self-loop + bias, write fp32
  for (int n = g; n < nNodes; n += 16) {
    float di = disl[n];
    float ws = di * di;
    const unsigned short* srow = hb + (size_t)(base + n) * 128;
    float* orow = outF + (size_t)(base + n) * 128;
    #pragma unroll
    for (int k = 0; k < 4; ++k) {
      int ch = q + 32 * k;
      orow[ch] = acc[n * 128 + ch] + bf2f(srow[ch]) * ws + bias[ch];
    }
  }
}

// ---------------- bucket aggregation (40 ch) + bias + softmax ----------------
__global__ __launch_bounds__(512) void agg40b(const unsigned short* __restrict__ hb40,
                                              const float* __restrict__ dis,
                                              const int* __restrict__ bucketStart,
                                              const unsigned* __restrict__ pairs,
                                              const float* __restrict__ b3,
                                              float* __restrict__ out, int N) {
  __shared__ float acc[128 * OUTC];   // 20.5 KB [node][ch]
  __shared__ float disl[128];
  int b = blockIdx.x;
  int base = b << 7;
  int nNodes = min(128, N - base);
  int t = threadIdx.x;
  for (int i = t; i < 128 * OUTC; i += 512) acc[i] = 0.f;
  if (t < 128) disl[t] = (t < nNodes) ? dis[base + t] : 0.f;
  __syncthreads();
  int e0 = bucketStart[b], e1 = bucketStart[b + 1];
  int q = t & 31;
  int g = t >> 5;
  for (int e = e0 + g; e < e1; e += 16) {
    unsigned p = pairs[e];
    int s = p & 0x1FFFF;
    int dl = p >> 17;
    float w = dis[s] * disl[dl];
    const unsigned short* row = hb40 + (size_t)s * OUTC;
    float* arow = acc + dl * OUTC;
    float v0 = bf2f(row[q]);
    atomicAdd(&arow[q], v0 * w);            // banks (8*dl+q)%32: distinct per group
    if (q < 8) {
      float v1 = bf2f(row[32 + q]);
      atomicAdd(&arow[32 + q], v1 * w);
    }
  }
  __syncthreads();
  // epilogue: self + bias + softmax; one wave per node
  int wid = t >> 6, lane = t & 63;
  for (int n = wid; n < nNodes; n += 8) {
    bool a = lane < OUTC;
    float v = -1e30f;
    if (a) {
      float di = disl[n];
      v = acc[n * OUTC + lane]
        + bf2f(hb40[(size_t)(base + n) * OUTC + lane]) * di * di
        + b3[lane];
    }
    float m = v;
    #pragma unroll
    for (int off = 32; off; off >>= 1) m = fmaxf(m, __shfl_xor(m, off));
    float ex = a ? __expf(v - m) : 0.f;
    float s = ex;
    #pragma unroll
    for (int off = 32; off; off >>= 1) s += __shfl_xor(s, off);
    if (a) out[(size_t)(base + n) * OUTC + lane] = ex / s;
  }
}

// ---------------- BatchNorm stats (float4 reads) ----------------
__global__ __launch_bounds__(256) void bn_stats(const float4* __restrict__ h,
                                                float* __restrict__ stats, int N) {
  int t = threadIdx.x;
  int q = t & 31;
  int rg = t >> 5;
  float4 s = make_float4(0.f, 0.f, 0.f, 0.f);
  float4 s2 = make_float4(0.f, 0.f, 0.f, 0.f);
  for (int r = blockIdx.x * 8 + rg; r < N; r += gridDim.x * 8) {
    float4 v = h[(size_t)r * 32 + q];
    s.x += v.x; s.y += v.y; s.z += v.z; s.w += v.w;
    s2.x += v.x * v.x; s2.y += v.y * v.y; s2.z += v.z * v.z; s2.w += v.w * v.w;
  }
  __shared__ float sm[256][8];
  sm[t][0] = s.x; sm[t][1] = s.y; sm[t][2] = s.z; sm[t][3] = s.w;
  sm[t][4] = s2.x; sm[t][5] = s2.y; sm[t][6] = s2.z; sm[t][7] = s2.w;
  __syncthreads();
  if (t < 32) {
    float a[8] = {0.f, 0.f, 0.f, 0.f, 0.f, 0.f, 0.f, 0.f};
    #pragma unroll
    for (int j = 0; j < 8; ++j)
      #pragma unroll
      for (int k = 0; k < 8; ++k) a[k] += sm[t + 32 * j][k];
    #pragma unroll
    for (int k = 0; k < 4; ++k) {
      atomicAdd(&stats[4 * t + k], a[k]);
      atomicAdd(&stats[128 + 4 * t + k], a[4 + k]);
    }
  }
}

__global__ void bn_scale(float* __restrict__ stats, const float* __restrict__ g,
                         const float* __restrict__ be, float invN) {
  int c = threadIdx.x;  // 128 threads
  float mean = stats[c] * invN;
  float var = stats[128 + c] * invN - mean * mean;
  float sc = g[c] * rsqrtf(var + BN_EPS);
  stats[256 + c] = sc;
  stats[384 + c] = be[c] - mean * sc;
}

// ---------------- launcher ----------------
extern "C" void kernel_launch(void* const* d_in, const int* in_sizes, int n_in,
                              void* d_out, int out_size, void* d_ws, size_t ws_size,
                              hipStream_t stream) {
  const float* x   = (const float*)d_in[0];
  const int*   ei  = (const int*)d_in[1];
  const float* W1  = (const float*)d_in[2];
  const float* b1  = (const float*)d_in[3];
  const float* g1  = (const float*)d_in[4];
  const float* be1 = (const float*)d_in[5];
  const float* W2  = (const float*)d_in[6];
  const float* b2  = (const float*)d_in[7];
  const float* g2  = (const float*)d_in[8];
  const float* be2 = (const float*)d_in[9];
  const float* W3  = (const float*)d_in[10];
  const float* b3  = (const float*)d_in[11];

  const int N = in_sizes[0] / HIDC;
  const int E = in_sizes[1] / 2;
  const int NBUK = (N + 127) >> 7;
  const int* srcI = ei;
  const int* dstI = ei + E;

  float* outSoft = (float*)d_out;                       // [N,40]
  float* outH    = (float*)d_out + (size_t)N * OUTC;    // [N,128]; preBN temp, then final h

  char* ws = (char*)d_ws;
  size_t off = 0;
  auto alloc = [&](size_t bytes) -> char* {
    char* p = ws + off;
    off += (bytes + 255) & ~(size_t)255;
    return p;
  };
  unsigned short* bufAbf  = (unsigned short*)alloc((size_t)N * HIDC * 2);  // gemm128 out (bf16)
  unsigned short* buf40bf = (unsigned short*)alloc((size_t)N * OUTC * 2);  // gemm40 out (bf16)
  float*    dis         = (float*)alloc((size_t)N * 4);
  float*    stats       = (float*)alloc(1024 * 4);
  int*      bucketCount = (int*)alloc((size_t)MAXBUK * 4);
  int*      bucketStart = (int*)alloc((size_t)(MAXBUK + 1) * 4);
  int*      cursor      = (int*)alloc((size_t)MAXBUK * 4);
  unsigned* pairs       = (unsigned*)alloc((size_t)E * 4);
  (void)ws_size; (void)n_in;

  hipMemsetAsync(bucketCount, 0, (size_t)MAXBUK * 4, stream);
  hipMemsetAsync(stats, 0, 1024 * 4, stream);

  // bucket-CSR build
  bin_hist<<<1024, 256, 0, stream>>>(dstI, bucketCount, E, NBUK);
  scan_buckets<<<1, 512, 0, stream>>>(bucketCount, bucketStart, cursor, NBUK, E);
  bin_scatter<<<(E + TILE - 1) / TILE, 512, 0, stream>>>(srcI, dstI, cursor, pairs, E, NBUK);
  bucket_dis<<<NBUK, 256, 0, stream>>>(pairs, bucketStart, dis, N);

  const float invN = 1.0f / (float)N;

  // ---- Layer 1 ----
  gemm128<false><<<(N + 63) / 64, 256, 0, stream>>>(x, W1, nullptr, nullptr, bufAbf, N);
  agg128b<<<NBUK, 512, 0, stream>>>(bufAbf, dis, bucketStart, pairs, b1, outH, N);
  bn_stats<<<512, 256, 0, stream>>>((const float4*)outH, stats, N);
  bn_scale<<<1, 128, 0, stream>>>(stats, g1, be1, invN);

  // ---- Layer 2 (BN1+ReLU fused into gemm load) ----
  gemm128<true><<<(N + 63) / 64, 256, 0, stream>>>(outH, W2, stats + 256, stats + 384,
                                                   bufAbf, N);
  agg128b<<<NBUK, 512, 0, stream>>>(bufAbf, dis, bucketStart, pairs, b2, outH, N);
  bn_stats<<<512, 256, 0, stream>>>((const float4*)outH, stats + 512, N);
  bn_scale<<<1, 128, 0, stream>>>(stats + 512, g2, be2, invN);

  // ---- Layer 3 (BN2+ReLU fused into gemm40 load; writes post-BN h back to outH) ----
  gemm40<<<(N + 255) / 256, 256, 0, stream>>>(outH, W3, stats + 768, stats + 896,
                                              buf40bf, N);
  agg40b<<<NBUK, 512, 0, stream>>>(buf40bf, dis, bucketStart, pairs, b3, outSoft, N);
}

// Round 5
// 709.503 us; speedup vs baseline: 5.1481x; 5.1481x over previous
//
#include <hip/hip_runtime.h>
#include <math.h>

#define HIDC 128
#define OUTC 40
#define BN_EPS 1e-5f
#define MAXBUK 784          // >= ceil(100000/128)
#define TILE 8192
#define BCAP 4096           // per-bucket LDS sort capacity (avg bucket ~2045)

// ---------------- bf16 helpers ----------------
__device__ __forceinline__ unsigned short f2bf(float f) {
  union { float f; unsigned u; } v; v.f = f;
  unsigned r = v.u + 0x7fff + ((v.u >> 16) & 1);   // RNE
  return (unsigned short)(r >> 16);
}
__device__ __forceinline__ float bf2f(unsigned short h) {
  union { unsigned u; float f; } v; v.u = ((unsigned)h) << 16;
  return v.f;
}

// ---------------- bucket-CSR build ----------------
// bucket b = dst >> 7 (128 nodes/bucket). pair = src | (dst&127)<<17  (src < 2^17).

__global__ __launch_bounds__(256) void bin_hist(const int* __restrict__ dst,
                                                int* __restrict__ bucketCount,
                                                int E, int NBUK) {
  __shared__ int h[MAXBUK];
  int t = threadIdx.x;
  for (int i = t; i < NBUK; i += 256) h[i] = 0;
  __syncthreads();
  int idx = blockIdx.x * 256 + t;
  int stride = gridDim.x * 256;
  for (int e = idx; e < E; e += stride) atomicAdd(&h[dst[e] >> 7], 1);
  __syncthreads();
  for (int i = t; i < NBUK; i += 256) if (h[i]) atomicAdd(&bucketCount[i], h[i]);
}

__global__ __launch_bounds__(512) void scan_buckets(const int* __restrict__ bucketCount,
                                                    int* __restrict__ bucketStart,
                                                    int* __restrict__ cursor,
                                                    int NBUK, int E) {
  __shared__ int ssc[512];
  int t = threadIdx.x;
  int c0 = (2 * t < NBUK) ? bucketCount[2 * t] : 0;
  int c1 = (2 * t + 1 < NBUK) ? bucketCount[2 * t + 1] : 0;
  ssc[t] = c0 + c1;
  __syncthreads();
  for (int off = 1; off < 512; off <<= 1) {
    int v = (t >= off) ? ssc[t - off] : 0;
    __syncthreads();
    ssc[t] += v;
    __syncthreads();
  }
  int base = ssc[t] - (c0 + c1);   // exclusive
  if (2 * t < NBUK)     { bucketStart[2 * t] = base;          cursor[2 * t] = base; }
  if (2 * t + 1 < NBUK) { bucketStart[2 * t + 1] = base + c0; cursor[2 * t + 1] = base + c0; }
  if (t == 511) bucketStart[NBUK] = E;
}

__global__ __launch_bounds__(512) void bin_scatter(const int* __restrict__ src,
                                                   const int* __restrict__ dst,
                                                   int* __restrict__ cursor,
                                                   unsigned* __restrict__ pairs,
                                                   int E, int NBUK) {
  __shared__ unsigned ord[TILE];
  __shared__ int hist[MAXBUK], scanS[MAXBUK], gbase[MAXBUK], rank[MAXBUK];
  __shared__ int ssc[512];
  int t = threadIdx.x;
  int tb = blockIdx.x * TILE;
  int nT = min(TILE, E - tb);
  for (int i = t; i < NBUK; i += 512) { hist[i] = 0; rank[i] = 0; }
  __syncthreads();
  for (int i = t; i < nT; i += 512) atomicAdd(&hist[dst[tb + i] >> 7], 1);
  __syncthreads();
  int c0 = (2 * t < NBUK) ? hist[2 * t] : 0;
  int c1 = (2 * t + 1 < NBUK) ? hist[2 * t + 1] : 0;
  ssc[t] = c0 + c1;
  __syncthreads();
  for (int off = 1; off < 512; off <<= 1) {
    int v = (t >= off) ? ssc[t - off] : 0;
    __syncthreads();
    ssc[t] += v;
    __syncthreads();
  }
  int bse = ssc[t] - (c0 + c1);
  if (2 * t < NBUK) scanS[2 * t] = bse;
  if (2 * t + 1 < NBUK) scanS[2 * t + 1] = bse + c0;
  __syncthreads();
  for (int i = t; i < NBUK; i += 512) {
    int c = hist[i];
    if (c) gbase[i] = atomicAdd(&cursor[i], c);
  }
  __syncthreads();
  for (int i = t; i < nT; i += 512) {
    int d = dst[tb + i], s = src[tb + i];
    int b = d >> 7;
    int pos = scanS[b] + atomicAdd(&rank[b], 1);
    ord[pos] = (unsigned)s | ((unsigned)(d & 127) << 17);
  }
  __syncthreads();
  // coalesced flush: wave per bucket round-robin
  int wid = t >> 6, lane = t & 63;
  for (int b = wid; b < NBUK; b += 8) {
    int c = hist[b];
    if (!c) continue;
    int gb = gbase[b], sb = scanS[b];
    for (int j = lane; j < c; j += 64) pairs[gb + j] = ord[sb + j];
  }
}

// per-bucket counting sort -> per-node CSR (coalesced writes) + counts/rowStart/dis
__global__ __launch_bounds__(256) void csr_from_pairs(const unsigned* __restrict__ pairs,
                                                      const int* __restrict__ bucketStart,
                                                      int* __restrict__ csrSrc,
                                                      int* __restrict__ counts,
                                                      int* __restrict__ rowStart,
                                                      float* __restrict__ dis, int N) {
  __shared__ int hist[128], excl[128], rank[128];
  __shared__ int ordS[BCAP];
  int b = blockIdx.x, t = threadIdx.x;
  int base = b << 7;
  int e0 = bucketStart[b], e1 = bucketStart[b + 1];
  int cnt = e1 - e0;
  if (t < 128) { hist[t] = 0; rank[t] = 0; }
  __syncthreads();
  for (int e = e0 + t; e < e1; e += 256) atomicAdd(&hist[pairs[e] >> 17], 1);
  __syncthreads();
  if (t < 128) excl[t] = hist[t];
  __syncthreads();
  for (int off = 1; off < 128; off <<= 1) {
    int v = (t < 128 && t >= off) ? excl[t - off] : 0;
    __syncthreads();
    if (t < 128) excl[t] += v;
    __syncthreads();
  }
  if (t < 128) excl[t] -= hist[t];   // exclusive
  __syncthreads();
  if (t < 128 && base + t < N) {
    int c = hist[t];
    counts[base + t] = c;
    rowStart[base + t] = e0 + excl[t];
    dis[base + t] = rsqrtf((float)(c + 1));
  }
  if (cnt <= BCAP) {
    for (int e = e0 + t; e < e1; e += 256) {
      unsigned p = pairs[e];
      int dl = p >> 17;
      int pos = excl[dl] + atomicAdd(&rank[dl], 1);
      ordS[pos] = (int)(p & 0x1FFFF);
    }
    __syncthreads();
    for (int j = t; j < cnt; j += 256) csrSrc[e0 + j] = ordS[j];
  } else {  // fallback (never expected for random graphs)
    for (int e = e0 + t; e < e1; e += 256) {
      unsigned p = pairs[e];
      int dl = p >> 17;
      int pos = excl[dl] + atomicAdd(&rank[dl], 1);
      csrSrc[e0 + pos] = (int)(p & 0x1FFFF);
    }
  }
}

// ---------------- GEMM: [N,128] x [128,128] -> bf16, optional fused BN+ReLU on A ----------------
template<bool BN>
__global__ __launch_bounds__(256) void gemm128(const float* __restrict__ A,
                                               const float* __restrict__ W,
                                               const float* __restrict__ bnsc,
                                               const float* __restrict__ bnsh,
                                               unsigned short* __restrict__ Cbf, int N) {
  __shared__ float Wl[128 * 128];
  __shared__ float Al[64][33];
  __shared__ float scs[128], shs[128];
  int t = threadIdx.x;
  for (int idx = t; idx < 128 * 128; idx += 256) Wl[idx] = W[idx];
  if (BN && t < 128) { scs[t] = bnsc[t]; shs[t] = bnsh[t]; }
  int tr = t >> 5;
  int tc = t & 31;
  int rowBase = blockIdx.x * 64;
  float4 acc[8];
  #pragma unroll
  for (int u = 0; u < 8; ++u) acc[u] = make_float4(0.f, 0.f, 0.f, 0.f);

  for (int kt = 0; kt < 128; kt += 32) {
    __syncthreads();
    #pragma unroll
    for (int u = 0; u < 8; ++u) {
      int id = u * 256 + t;
      int r = id >> 5, col = id & 31;
      int gr = rowBase + r;
      float v = (gr < N) ? A[(size_t)gr * 128 + kt + col] : 0.f;
      if (BN) v = fmaxf(v * scs[kt + col] + shs[kt + col], 0.f);
      Al[r][col] = v;
    }
    __syncthreads();
    #pragma unroll
    for (int kk = 0; kk < 32; ++kk) {
      float4 wv = *(const float4*)&Wl[(kt + kk) * 128 + 4 * tc];
      #pragma unroll
      for (int u = 0; u < 8; ++u) {
        float a = Al[tr * 8 + u][kk];
        acc[u].x += a * wv.x; acc[u].y += a * wv.y;
        acc[u].z += a * wv.z; acc[u].w += a * wv.w;
      }
    }
  }
  #pragma unroll
  for (int u = 0; u < 8; ++u) {
    int gr = rowBase + tr * 8 + u;
    if (gr < N) {
      ushort4 o;
      o.x = f2bf(acc[u].x); o.y = f2bf(acc[u].y);
      o.z = f2bf(acc[u].z); o.w = f2bf(acc[u].w);
      *(ushort4*)&Cbf[(size_t)gr * 128 + 4 * tc] = o;
    }
  }
}

// ---------------- GEMM: [N,128] x [128,40] with fused BN+ReLU on A; writes post-BN A back ----------------
__global__ __launch_bounds__(256) void gemm40(float* __restrict__ A,
                                              const float* __restrict__ W,
                                              const float* __restrict__ bnsc,
                                              const float* __restrict__ bnsh,
                                              unsigned short* __restrict__ Cbf, int N) {
  __shared__ float Wl[128 * OUTC];
  __shared__ float Al[256 * 17];
  __shared__ float scs[128], shs[128];
  int t = threadIdx.x;
  for (int idx = t; idx < 128 * OUTC; idx += 256) Wl[idx] = W[idx];
  if (t < 128) { scs[t] = bnsc[t]; shs[t] = bnsh[t]; }
  int rowBase = blockIdx.x * 256;
  float acc[OUTC];
  #pragma unroll
  for (int c = 0; c < OUTC; ++c) acc[c] = 0.f;

  for (int kt = 0; kt < 128; kt += 16) {
    __syncthreads();
    #pragma unroll
    for (int u = 0; u < 16; ++u) {
      int id = u * 256 + t;
      int r = id >> 4, col = id & 15;
      int gr = rowBase + r;
      if (gr < N) {
        float v = A[(size_t)gr * 128 + kt + col];
        v = fmaxf(v * scs[kt + col] + shs[kt + col], 0.f);
        Al[r * 17 + col] = v;
        A[(size_t)gr * 128 + kt + col] = v;   // h output (post-BN+ReLU)
      } else {
        Al[r * 17 + col] = 0.f;
      }
    }
    __syncthreads();
    #pragma unroll
    for (int kk = 0; kk < 16; ++kk) {
      float a = Al[t * 17 + kk];
      const float* wr = &Wl[(kt + kk) * OUTC];
      #pragma unroll
      for (int c = 0; c < OUTC; ++c) acc[c] += a * wr[c];
    }
  }
  int gr = rowBase + t;
  if (gr < N) {
    unsigned short* cr = Cbf + (size_t)gr * OUTC;
    #pragma unroll
    for (int c4 = 0; c4 < OUTC; c4 += 4) {
      ushort4 o;
      o.x = f2bf(acc[c4]); o.y = f2bf(acc[c4 + 1]);
      o.z = f2bf(acc[c4 + 2]); o.w = f2bf(acc[c4 + 3]);
      *(ushort4*)&cr[c4] = o;
    }
  }
}

// ---------------- aggregation (128 ch, bf16 source): 32 threads/node ----------------
__global__ __launch_bounds__(256) void agg128(const unsigned short* __restrict__ hb,
                                              const float* __restrict__ dis,
                                              const int* __restrict__ rowStart,
                                              const int* __restrict__ counts,
                                              const int* __restrict__ csrSrc,
                                              const float* __restrict__ bias,
                                              float4* __restrict__ out4, int N) {
  int g = threadIdx.x >> 5;
  int q = threadIdx.x & 31;          // owns channels 4q..4q+3
  int i = blockIdx.x * 8 + g;
  if (i >= N) return;
  const ushort4* base = (const ushort4*)hb;  // row = 32 ushort4
  float di = dis[i];
  float wself = di * di;
  ushort4 sv = base[(size_t)i * 32 + q];
  float4 acc;
  acc.x = bf2f(sv.x) * wself; acc.y = bf2f(sv.y) * wself;
  acc.z = bf2f(sv.z) * wself; acc.w = bf2f(sv.w) * wself;
  int s0 = rowStart[i];
  int cnt = counts[i];
  int e = 0;
  for (; e + 3 < cnt; e += 4) {
    int sA = csrSrc[s0 + e],     sB = csrSrc[s0 + e + 1];
    int sC = csrSrc[s0 + e + 2], sD = csrSrc[s0 + e + 3];
    float wA = dis[sA] * di, wB = dis[sB] * di;
    float wC = dis[sC] * di, wD = dis[sD] * di;
    ushort4 vA = base[(size_t)sA * 32 + q];
    ushort4 vB = base[(size_t)sB * 32 + q];
    ushort4 vC = base[(size_t)sC * 32 + q];
    ushort4 vD = base[(size_t)sD * 32 + q];
    acc.x += bf2f(vA.x) * wA; acc.y += bf2f(vA.y) * wA;
    acc.z += bf2f(vA.z) * wA; acc.w += bf2f(vA.w) * wA;
    acc.x += bf2f(vB.x) * wB; acc.y += bf2f(vB.y) * wB;
    acc.z += bf2f(vB.z) * wB; acc.w += bf2f(vB.w) * wB;
    acc.x += bf2f(vC.x) * wC; acc.y += bf2f(vC.y) * wC;
    acc.z += bf2f(vC.z) * wC; acc.w += bf2f(vC.w) * wC;
    acc.x += bf2f(vD.x) * wD; acc.y += bf2f(vD.y) * wD;
    acc.z += bf2f(vD.z) * wD; acc.w += bf2f(vD.w) * wD;
  }
  for (; e < cnt; ++e) {
    int sA = csrSrc[s0 + e];
    float wA = dis[sA] * di;
    ushort4 vA = base[(size_t)sA * 32 + q];
    acc.x += bf2f(vA.x) * wA; acc.y += bf2f(vA.y) * wA;
    acc.z += bf2f(vA.z) * wA; acc.w += bf2f(vA.w) * wA;
  }
  float4 b = ((const float4*)bias)[q];
  acc.x += b.x; acc.y += b.y; acc.z += b.z; acc.w += b.w;
  out4[(size_t)i * 32 + q] = acc;
}

// ---------------- BatchNorm stats (float4 reads) ----------------
__global__ __launch_bounds__(256) void bn_stats(const float4* __restrict__ h,
                                                float* __restrict__ stats, int N) {
  int t = threadIdx.x;
  int q = t & 31;
  int rg = t >> 5;
  float4 s = make_float4(0.f, 0.f, 0.f, 0.f);
  float4 s2 = make_float4(0.f, 0.f, 0.f, 0.f);
  for (int r = blockIdx.x * 8 + rg; r < N; r += gridDim.x * 8) {
    float4 v = h[(size_t)r * 32 + q];
    s.x += v.x; s.y += v.y; s.z += v.z; s.w += v.w;
    s2.x += v.x * v.x; s2.y += v.y * v.y; s2.z += v.z * v.z; s2.w += v.w * v.w;
  }
  __shared__ float sm[256][8];
  sm[t][0] = s.x; sm[t][1] = s.y; sm[t][2] = s.z; sm[t][3] = s.w;
  sm[t][4] = s2.x; sm[t][5] = s2.y; sm[t][6] = s2.z; sm[t][7] = s2.w;
  __syncthreads();
  if (t < 32) {
    float a[8] = {0.f, 0.f, 0.f, 0.f, 0.f, 0.f, 0.f, 0.f};
    #pragma unroll
    for (int j = 0; j < 8; ++j)
      #pragma unroll
      for (int k = 0; k < 8; ++k) a[k] += sm[t + 32 * j][k];
    #pragma unroll
    for (int k = 0; k < 4; ++k) {
      atomicAdd(&stats[4 * t + k], a[k]);
      atomicAdd(&stats[128 + 4 * t + k], a[4 + k]);
    }
  }
}

__global__ void bn_scale(float* __restrict__ stats, const float* __restrict__ g,
                         const float* __restrict__ be, float invN) {
  int c = threadIdx.x;  // 128 threads
  float mean = stats[c] * invN;
  float var = stats[128 + c] * invN - mean * mean;
  float sc = g[c] * rsqrtf(var + BN_EPS);
  stats[256 + c] = sc;
  stats[384 + c] = be[c] - mean * sc;
}

// ---------------- layer-3 aggregation + bias + softmax (16 lanes/node, bf16 source) ----------------
__global__ __launch_bounds__(256) void agg40_softmax(const unsigned short* __restrict__ hb,
                                                     const float* __restrict__ dis,
                                                     const int* __restrict__ rowStart,
                                                     const int* __restrict__ counts,
                                                     const int* __restrict__ csrSrc,
                                                     const float* __restrict__ b3,
                                                     float* __restrict__ out, int N) {
  int l = threadIdx.x & 15;      // lanes 0..9 active (10*4 = 40 ch)
  int g = threadIdx.x >> 4;      // 16 nodes/block
  int i = blockIdx.x * 16 + g;
  if (i >= N) return;
  bool act = l < 10;
  float di = dis[i];
  float4 acc = make_float4(0.f, 0.f, 0.f, 0.f);
  if (act) {
    ushort4 sv = *(const ushort4*)&hb[(size_t)i * OUTC + l * 4];
    float w = di * di;
    acc.x = bf2f(sv.x) * w; acc.y = bf2f(sv.y) * w;
    acc.z = bf2f(sv.z) * w; acc.w = bf2f(sv.w) * w;
  }
  int s0 = rowStart[i];
  int cnt = counts[i];
  int e = 0;
  for (; e + 1 < cnt; e += 2) {
    int sA = csrSrc[s0 + e], sB = csrSrc[s0 + e + 1];
    float wA = dis[sA] * di, wB = dis[sB] * di;
    if (act) {
      ushort4 vA = *(const ushort4*)&hb[(size_t)sA * OUTC + l * 4];
      ushort4 vB = *(const ushort4*)&hb[(size_t)sB * OUTC + l * 4];
      acc.x += bf2f(vA.x) * wA; acc.y += bf2f(vA.y) * wA;
      acc.z += bf2f(vA.z) * wA; acc.w += bf2f(vA.w) * wA;
      acc.x += bf2f(vB.x) * wB; acc.y += bf2f(vB.y) * wB;
      acc.z += bf2f(vB.z) * wB; acc.w += bf2f(vB.w) * wB;
    }
  }
  if (e < cnt) {
    int sA = csrSrc[s0 + e];
    float wA = dis[sA] * di;
    if (act) {
      ushort4 vA = *(const ushort4*)&hb[(size_t)sA * OUTC + l * 4];
      acc.x += bf2f(vA.x) * wA; acc.y += bf2f(vA.y) * wA;
      acc.z += bf2f(vA.z) * wA; acc.w += bf2f(vA.w) * wA;
    }
  }
  if (act) {
    float4 b = ((const float4*)b3)[l];
    acc.x += b.x; acc.y += b.y; acc.z += b.z; acc.w += b.w;
  }
  float m = act ? fmaxf(fmaxf(acc.x, acc.y), fmaxf(acc.z, acc.w)) : -1e30f;
  #pragma unroll
  for (int off = 8; off; off >>= 1) m = fmaxf(m, __shfl_xor(m, off, 16));
  float4 ex = make_float4(0.f, 0.f, 0.f, 0.f);
  float lsum = 0.f;
  if (act) {
    ex.x = __expf(acc.x - m); ex.y = __expf(acc.y - m);
    ex.z = __expf(acc.z - m); ex.w = __expf(acc.w - m);
    lsum = ex.x + ex.y + ex.z + ex.w;
  }
  #pragma unroll
  for (int off = 8; off; off >>= 1) lsum += __shfl_xor(lsum, off, 16);
  if (act) {
    float inv = 1.0f / lsum;
    float4 o;
    o.x = ex.x * inv; o.y = ex.y * inv; o.z = ex.z * inv; o.w = ex.w * inv;
    *(float4*)&out[(size_t)i * OUTC + l * 4] = o;
  }
}

// ---------------- launcher ----------------
extern "C" void kernel_launch(void* const* d_in, const int* in_sizes, int n_in,
                              void* d_out, int out_size, void* d_ws, size_t ws_size,
                              hipStream_t stream) {
  const float* x   = (const float*)d_in[0];
  const int*   ei  = (const int*)d_in[1];
  const float* W1  = (const float*)d_in[2];
  const float* b1  = (const float*)d_in[3];
  const float* g1  = (const float*)d_in[4];
  const float* be1 = (const float*)d_in[5];
  const float* W2  = (const float*)d_in[6];
  const float* b2  = (const float*)d_in[7];
  const float* g2  = (const float*)d_in[8];
  const float* be2 = (const float*)d_in[9];
  const float* W3  = (const float*)d_in[10];
  const float* b3  = (const float*)d_in[11];

  const int N = in_sizes[0] / HIDC;
  const int E = in_sizes[1] / 2;
  const int NBUK = (N + 127) >> 7;
  const int* srcI = ei;
  const int* dstI = ei + E;

  float* outSoft = (float*)d_out;                       // [N,40]
  float* outH    = (float*)d_out + (size_t)N * OUTC;    // [N,128]; preBN temp, then final h

  char* ws = (char*)d_ws;
  size_t off = 0;
  auto alloc = [&](size_t bytes) -> char* {
    char* p = ws + off;
    off += (bytes + 255) & ~(size_t)255;
    return p;
  };
  unsigned short* bufAbf  = (unsigned short*)alloc((size_t)N * HIDC * 2);  // gemm128 out (bf16)
  unsigned short* buf40bf = (unsigned short*)alloc((size_t)N * OUTC * 2);  // gemm40 out (bf16)
  float*    dis         = (float*)alloc((size_t)N * 4);
  float*    stats       = (float*)alloc(1024 * 4);
  int*      bucketCount = (int*)alloc((size_t)MAXBUK * 4);
  int*      bucketStart = (int*)alloc((size_t)(MAXBUK + 1) * 4);
  int*      cursor      = (int*)alloc((size_t)MAXBUK * 4);
  int*      counts      = (int*)alloc((size_t)N * 4);
  int*      rowStart    = (int*)alloc((size_t)N * 4);
  unsigned* pairs       = (unsigned*)alloc((size_t)E * 4);
  int*      csrSrc      = (int*)alloc((size_t)E * 4);
  (void)ws_size; (void)n_in;

  hipMemsetAsync(bucketCount, 0, (size_t)MAXBUK * 4, stream);
  hipMemsetAsync(stats, 0, 1024 * 4, stream);

  // bucket-sorted CSR build (all writes coalesced)
  bin_hist<<<512, 256, 0, stream>>>(dstI, bucketCount, E, NBUK);
  scan_buckets<<<1, 512, 0, stream>>>(bucketCount, bucketStart, cursor, NBUK, E);
  bin_scatter<<<(E + TILE - 1) / TILE, 512, 0, stream>>>(srcI, dstI, cursor, pairs, E, NBUK);
  csr_from_pairs<<<NBUK, 256, 0, stream>>>(pairs, bucketStart, csrSrc, counts, rowStart,
                                           dis, N);

  const float invN = 1.0f / (float)N;

  // ---- Layer 1 ----
  gemm128<false><<<(N + 63) / 64, 256, 0, stream>>>(x, W1, nullptr, nullptr, bufAbf, N);
  agg128<<<(N + 7) / 8, 256, 0, stream>>>(bufAbf, dis, rowStart, counts, csrSrc,
                                          b1, (float4*)outH, N);
  bn_stats<<<512, 256, 0, stream>>>((const float4*)outH, stats, N);
  bn_scale<<<1, 128, 0, stream>>>(stats, g1, be1, invN);

  // ---- Layer 2 (BN1+ReLU fused into gemm load) ----
  gemm128<true><<<(N + 63) / 64, 256, 0, stream>>>(outH, W2, stats + 256, stats + 384,
                                                   bufAbf, N);
  agg128<<<(N + 7) / 8, 256, 0, stream>>>(bufAbf, dis, rowStart, counts, csrSrc,
                                          b2, (float4*)outH, N);
  bn_stats<<<512, 256, 0, stream>>>((const float4*)outH, stats + 512, N);
  bn_scale<<<1, 128, 0, stream>>>(stats + 512, g2, be2, invN);

  // ---- Layer 3 (BN2+ReLU fused into gemm40 load; writes post-BN h back to outH) ----
  gemm40<<<(N + 255) / 256, 256, 0, stream>>>(outH, W3, stats + 768, stats + 896,
                                              buf40bf, N);
  agg40_softmax<<<(N + 15) / 16, 256, 0, stream>>>(buf40bf, dis, rowStart, counts,
                                                   csrSrc, b3, outSoft, N);
}

// Round 6
// 580.333 us; speedup vs baseline: 6.2940x; 1.2226x over previous
//
#include <hip/hip_runtime.h>
#include <math.h>

#define HIDC 128
#define OUTC 40
#define BN_EPS 1e-5f
#define MAXBUK 784          // >= ceil(100000/128)
#define TILE 8192
#define BCAP 4096           // per-bucket LDS sort capacity (avg bucket ~2045)

typedef __attribute__((ext_vector_type(8))) short bf16x8;
typedef __attribute__((ext_vector_type(4))) float f32x4;

// ---------------- bf16 helpers ----------------
__device__ __forceinline__ unsigned short f2bf(float f) {
  union { float f; unsigned u; } v; v.f = f;
  unsigned r = v.u + 0x7fff + ((v.u >> 16) & 1);   // RNE
  return (unsigned short)(r >> 16);
}
__device__ __forceinline__ float bf2f(unsigned short h) {
  union { unsigned u; float f; } v; v.u = ((unsigned)h) << 16;
  return v.f;
}

// ---------------- bucket-CSR build ----------------
// bucket b = dst >> 7 (128 nodes/bucket). pair = src | (dst&127)<<17  (src < 2^17).

__global__ __launch_bounds__(256) void bin_hist(const int* __restrict__ dst,
                                                int* __restrict__ bucketCount,
                                                int E, int NBUK) {
  __shared__ int h[MAXBUK];
  int t = threadIdx.x;
  for (int i = t; i < NBUK; i += 256) h[i] = 0;
  __syncthreads();
  int idx = blockIdx.x * 256 + t;
  int stride = gridDim.x * 256;
  for (int e = idx; e < E; e += stride) atomicAdd(&h[dst[e] >> 7], 1);
  __syncthreads();
  for (int i = t; i < NBUK; i += 256) if (h[i]) atomicAdd(&bucketCount[i], h[i]);
}

__global__ __launch_bounds__(512) void scan_buckets(const int* __restrict__ bucketCount,
                                                    int* __restrict__ bucketStart,
                                                    int* __restrict__ cursor,
                                                    int NBUK, int E) {
  __shared__ int ssc[512];
  int t = threadIdx.x;
  int c0 = (2 * t < NBUK) ? bucketCount[2 * t] : 0;
  int c1 = (2 * t + 1 < NBUK) ? bucketCount[2 * t + 1] : 0;
  ssc[t] = c0 + c1;
  __syncthreads();
  for (int off = 1; off < 512; off <<= 1) {
    int v = (t >= off) ? ssc[t - off] : 0;
    __syncthreads();
    ssc[t] += v;
    __syncthreads();
  }
  int base = ssc[t] - (c0 + c1);   // exclusive
  if (2 * t < NBUK)     { bucketStart[2 * t] = base;          cursor[2 * t] = base; }
  if (2 * t + 1 < NBUK) { bucketStart[2 * t + 1] = base + c0; cursor[2 * t + 1] = base + c0; }
  if (t == 511) bucketStart[NBUK] = E;
}

__global__ __launch_bounds__(512) void bin_scatter(const int* __restrict__ src,
                                                   const int* __restrict__ dst,
                                                   int* __restrict__ cursor,
                                                   unsigned* __restrict__ pairs,
                                                   int E, int NBUK) {
  __shared__ unsigned ord[TILE];
  __shared__ int hist[MAXBUK], scanS[MAXBUK], gbase[MAXBUK], rank[MAXBUK];
  __shared__ int ssc[512];
  int t = threadIdx.x;
  int tb = blockIdx.x * TILE;
  int nT = min(TILE, E - tb);
  for (int i = t; i < NBUK; i += 512) { hist[i] = 0; rank[i] = 0; }
  __syncthreads();
  for (int i = t; i < nT; i += 512) atomicAdd(&hist[dst[tb + i] >> 7], 1);
  __syncthreads();
  int c0 = (2 * t < NBUK) ? hist[2 * t] : 0;
  int c1 = (2 * t + 1 < NBUK) ? hist[2 * t + 1] : 0;
  ssc[t] = c0 + c1;
  __syncthreads();
  for (int off = 1; off < 512; off <<= 1) {
    int v = (t >= off) ? ssc[t - off] : 0;
    __syncthreads();
    ssc[t] += v;
    __syncthreads();
  }
  int bse = ssc[t] - (c0 + c1);
  if (2 * t < NBUK) scanS[2 * t] = bse;
  if (2 * t + 1 < NBUK) scanS[2 * t + 1] = bse + c0;
  __syncthreads();
  for (int i = t; i < NBUK; i += 512) {
    int c = hist[i];
    if (c) gbase[i] = atomicAdd(&cursor[i], c);
  }
  __syncthreads();
  for (int i = t; i < nT; i += 512) {
    int d = dst[tb + i], s = src[tb + i];
    int b = d >> 7;
    int pos = scanS[b] + atomicAdd(&rank[b], 1);
    ord[pos] = (unsigned)s | ((unsigned)(d & 127) << 17);
  }
  __syncthreads();
  // coalesced flush: wave per bucket round-robin
  int wid = t >> 6, lane = t & 63;
  for (int b = wid; b < NBUK; b += 8) {
    int c = hist[b];
    if (!c) continue;
    int gb = gbase[b], sb = scanS[b];
    for (int j = lane; j < c; j += 64) pairs[gb + j] = ord[sb + j];
  }
}

// per-bucket counting sort -> per-node CSR (coalesced writes) + counts/rowStart/dis
__global__ __launch_bounds__(256) void csr_from_pairs(const unsigned* __restrict__ pairs,
                                                      const int* __restrict__ bucketStart,
                                                      int* __restrict__ csrSrc,
                                                      int* __restrict__ counts,
                                                      int* __restrict__ rowStart,
                                                      float* __restrict__ dis, int N) {
  __shared__ int hist[128], excl[128], rank[128];
  __shared__ int ordS[BCAP];
  int b = blockIdx.x, t = threadIdx.x;
  int base = b << 7;
  int e0 = bucketStart[b], e1 = bucketStart[b + 1];
  int cnt = e1 - e0;
  if (t < 128) { hist[t] = 0; rank[t] = 0; }
  __syncthreads();
  for (int e = e0 + t; e < e1; e += 256) atomicAdd(&hist[pairs[e] >> 17], 1);
  __syncthreads();
  if (t < 128) excl[t] = hist[t];
  __syncthreads();
  for (int off = 1; off < 128; off <<= 1) {
    int v = (t < 128 && t >= off) ? excl[t - off] : 0;
    __syncthreads();
    if (t < 128) excl[t] += v;
    __syncthreads();
  }
  if (t < 128) excl[t] -= hist[t];   // exclusive
  __syncthreads();
  if (t < 128 && base + t < N) {
    int c = hist[t];
    counts[base + t] = c;
    rowStart[base + t] = e0 + excl[t];
    dis[base + t] = rsqrtf((float)(c + 1));
  }
  if (cnt <= BCAP) {
    for (int e = e0 + t; e < e1; e += 256) {
      unsigned p = pairs[e];
      int dl = p >> 17;
      int pos = excl[dl] + atomicAdd(&rank[dl], 1);
      ordS[pos] = (int)(p & 0x1FFFF);
    }
    __syncthreads();
    for (int j = t; j < cnt; j += 256) csrSrc[e0 + j] = ordS[j];
  } else {  // fallback
    for (int e = e0 + t; e < e1; e += 256) {
      unsigned p = pairs[e];
      int dl = p >> 17;
      int pos = excl[dl] + atomicAdd(&rank[dl], 1);
      csrSrc[e0 + pos] = (int)(p & 0x1FFFF);
    }
  }
}

// ---------------- W prep: W [128k][128n] fp32 -> W^T bf16, XOR-swizzled in k ----------------
// element (n,k) stored at n*128 + (k ^ ((n&15)<<3))  -> gemm stages it LINEARLY into LDS
__global__ __launch_bounds__(256) void wprep(const float* __restrict__ W1,
                                             const float* __restrict__ W2,
                                             unsigned short* __restrict__ W1s,
                                             unsigned short* __restrict__ W2s) {
  const float* W = blockIdx.x ? W2 : W1;
  unsigned short* Ws = blockIdx.x ? W2s : W1s;
  int t = threadIdx.x;
  for (int idx = t; idx < 128 * 128; idx += 256) {
    int n = idx >> 7, k = idx & 127;
    Ws[n * 128 + (k ^ ((n & 15) << 3))] = f2bf(W[k * 128 + n]);
  }
}

// ---------------- MFMA GEMM: [N,128] x [128,128] -> bf16, optional fused BN+ReLU on A ----------------
// 64 rows/block, 4 waves; wave w owns rows 16w..16w+15, all 128 cols (8 n-tiles).
template<bool BN>
__global__ __launch_bounds__(256) void gemm128m(const float* __restrict__ A,
                                                const unsigned short* __restrict__ Wsz,
                                                const float* __restrict__ bnsc,
                                                const float* __restrict__ bnsh,
                                                unsigned short* __restrict__ Cbf, int N) {
  __shared__ unsigned short Asw[64 * 128];    // 16 KB, XOR-swizzled
  __shared__ unsigned short Wsw[128 * 128];   // 32 KB, pre-swizzled (linear copy)
  __shared__ float scs[128], shs[128];
  int t = threadIdx.x;
  int rowBase = blockIdx.x * 64;

  if (BN && t < 128) { scs[t] = bnsc[t]; shs[t] = bnsh[t]; }
  __syncthreads();

  // stage W: linear coalesced copy (swizzle already applied in global)
  {
    const float4* wg = (const float4*)Wsz;   // 32768 B = 2048 float4
    float4* wl = (float4*)Wsw;
    #pragma unroll
    for (int i = 0; i < 8; ++i) wl[t + 256 * i] = wg[t + 256 * i];
  }
  // stage A: fp32 -> (BN+ReLU) -> bf16, swizzled ds_write_b128
  {
    int r = t >> 2;                // 0..63
    int kc = (t & 3) << 5;         // 0,32,64,96
    int gr = rowBase + r;
    const float* arow = A + (size_t)gr * 128 + kc;
    #pragma unroll
    for (int j = 0; j < 4; ++j) {
      int k0 = kc + j * 8;
      float v[8];
      if (gr < N) {
        float4 a = *(const float4*)(arow + j * 8);
        float4 b = *(const float4*)(arow + j * 8 + 4);
        v[0] = a.x; v[1] = a.y; v[2] = a.z; v[3] = a.w;
        v[4] = b.x; v[5] = b.y; v[6] = b.z; v[7] = b.w;
      } else {
        #pragma unroll
        for (int i = 0; i < 8; ++i) v[i] = 0.f;
      }
      if (BN) {
        #pragma unroll
        for (int i = 0; i < 8; ++i) v[i] = fmaxf(v[i] * scs[k0 + i] + shs[k0 + i], 0.f);
      }
      bf16x8 sv;
      #pragma unroll
      for (int i = 0; i < 8; ++i) sv[i] = (short)f2bf(v[i]);
      *(bf16x8*)&Asw[r * 128 + (k0 ^ ((r & 15) << 3))] = sv;
    }
  }
  __syncthreads();

  int w = t >> 6, l = t & 63;
  int lr = l & 15;
  int lk = (l >> 4) << 3;
  f32x4 acc[8];
  #pragma unroll
  for (int nt = 0; nt < 8; ++nt) acc[nt] = (f32x4){0.f, 0.f, 0.f, 0.f};

  #pragma unroll
  for (int kt = 0; kt < 128; kt += 32) {
    int ka = kt + lk;
    int kx = ka ^ (lr << 3);
    bf16x8 af = *(const bf16x8*)&Asw[(w * 16 + lr) * 128 + kx];
    #pragma unroll
    for (int nt = 0; nt < 8; ++nt) {
      bf16x8 bf = *(const bf16x8*)&Wsw[(nt * 16 + lr) * 128 + kx];
      acc[nt] = __builtin_amdgcn_mfma_f32_16x16x32_bf16(af, bf, acc[nt], 0, 0, 0);
    }
  }

  // store: D[m][n], m = (l>>4)*4 + reg (within wave's 16 rows), n = nt*16 + lr
  int m0 = rowBase + w * 16 + ((l >> 4) << 2);
  #pragma unroll
  for (int i = 0; i < 4; ++i) {
    int gm = m0 + i;
    if (gm < N) {
      unsigned short* cr = Cbf + (size_t)gm * 128 + lr;
      #pragma unroll
      for (int nt = 0; nt < 8; ++nt) cr[nt * 16] = f2bf(acc[nt][i]);
    }
  }
}

// ---------------- GEMM: [N,128] x [128,40] with fused BN+ReLU on A; writes post-BN A back ----------------
__global__ __launch_bounds__(256) void gemm40(float* __restrict__ A,
                                              const float* __restrict__ W,
                                              const float* __restrict__ bnsc,
                                              const float* __restrict__ bnsh,
                                              unsigned short* __restrict__ Cbf, int N) {
  __shared__ float Wl[128 * OUTC];
  __shared__ float Al[256 * 17];
  __shared__ float scs[128], shs[128];
  int t = threadIdx.x;
  for (int idx = t; idx < 128 * OUTC; idx += 256) Wl[idx] = W[idx];
  if (t < 128) { scs[t] = bnsc[t]; shs[t] = bnsh[t]; }
  int rowBase = blockIdx.x * 256;
  float acc[OUTC];
  #pragma unroll
  for (int c = 0; c < OUTC; ++c) acc[c] = 0.f;

  for (int kt = 0; kt < 128; kt += 16) {
    __syncthreads();
    #pragma unroll
    for (int u = 0; u < 16; ++u) {
      int id = u * 256 + t;
      int r = id >> 4, col = id & 15;
      int gr = rowBase + r;
      if (gr < N) {
        float v = A[(size_t)gr * 128 + kt + col];
        v = fmaxf(v * scs[kt + col] + shs[kt + col], 0.f);
        Al[r * 17 + col] = v;
        A[(size_t)gr * 128 + kt + col] = v;   // h output (post-BN+ReLU)
      } else {
        Al[r * 17 + col] = 0.f;
      }
    }
    __syncthreads();
    #pragma unroll
    for (int kk = 0; kk < 16; ++kk) {
      float a = Al[t * 17 + kk];
      const float* wr = &Wl[(kt + kk) * OUTC];
      #pragma unroll
      for (int c = 0; c < OUTC; ++c) acc[c] += a * wr[c];
    }
  }
  int gr = rowBase + t;
  if (gr < N) {
    unsigned short* cr = Cbf + (size_t)gr * OUTC;
    #pragma unroll
    for (int c4 = 0; c4 < OUTC; c4 += 4) {
      ushort4 o;
      o.x = f2bf(acc[c4]); o.y = f2bf(acc[c4 + 1]);
      o.z = f2bf(acc[c4 + 2]); o.w = f2bf(acc[c4 + 3]);
      *(ushort4*)&cr[c4] = o;
    }
  }
}

// ---------------- aggregation (128 ch, bf16 source): 32 threads/node ----------------
__global__ __launch_bounds__(256) void agg128(const unsigned short* __restrict__ hb,
                                              const float* __restrict__ dis,
                                              const int* __restrict__ rowStart,
                                              const int* __restrict__ counts,
                                              const int* __restrict__ csrSrc,
                                              const float* __restrict__ bias,
                                              float4* __restrict__ out4, int N) {
  int g = threadIdx.x >> 5;
  int q = threadIdx.x & 31;          // owns channels 4q..4q+3
  int i = blockIdx.x * 8 + g;
  if (i >= N) return;
  const ushort4* base = (const ushort4*)hb;  // row = 32 ushort4
  float di = dis[i];
  float wself = di * di;
  ushort4 sv = base[(size_t)i * 32 + q];
  float4 acc;
  acc.x = bf2f(sv.x) * wself; acc.y = bf2f(sv.y) * wself;
  acc.z = bf2f(sv.z) * wself; acc.w = bf2f(sv.w) * wself;
  int s0 = rowStart[i];
  int cnt = counts[i];
  int e = 0;
  for (; e + 3 < cnt; e += 4) {
    int sA = csrSrc[s0 + e],     sB = csrSrc[s0 + e + 1];
    int sC = csrSrc[s0 + e + 2], sD = csrSrc[s0 + e + 3];
    float wA = dis[sA] * di, wB = dis[sB] * di;
    float wC = dis[sC] * di, wD = dis[sD] * di;
    ushort4 vA = base[(size_t)sA * 32 + q];
    ushort4 vB = base[(size_t)sB * 32 + q];
    ushort4 vC = base[(size_t)sC * 32 + q];
    ushort4 vD = base[(size_t)sD * 32 + q];
    acc.x += bf2f(vA.x) * wA; acc.y += bf2f(vA.y) * wA;
    acc.z += bf2f(vA.z) * wA; acc.w += bf2f(vA.w) * wA;
    acc.x += bf2f(vB.x) * wB; acc.y += bf2f(vB.y) * wB;
    acc.z += bf2f(vB.z) * wB; acc.w += bf2f(vB.w) * wB;
    acc.x += bf2f(vC.x) * wC; acc.y += bf2f(vC.y) * wC;
    acc.z += bf2f(vC.z) * wC; acc.w += bf2f(vC.w) * wC;
    acc.x += bf2f(vD.x) * wD; acc.y += bf2f(vD.y) * wD;
    acc.z += bf2f(vD.z) * wD; acc.w += bf2f(vD.w) * wD;
  }
  for (; e < cnt; ++e) {
    int sA = csrSrc[s0 + e];
    float wA = dis[sA] * di;
    ushort4 vA = base[(size_t)sA * 32 + q];
    acc.x += bf2f(vA.x) * wA; acc.y += bf2f(vA.y) * wA;
    acc.z += bf2f(vA.z) * wA; acc.w += bf2f(vA.w) * wA;
  }
  float4 b = ((const float4*)bias)[q];
  acc.x += b.x; acc.y += b.y; acc.z += b.z; acc.w += b.w;
  out4[(size_t)i * 32 + q] = acc;
}

// ---------------- BatchNorm stats (float4 reads) ----------------
__global__ __launch_bounds__(256) void bn_stats(const float4* __restrict__ h,
                                                float* __restrict__ stats, int N) {
  int t = threadIdx.x;
  int q = t & 31;
  int rg = t >> 5;
  float4 s = make_float4(0.f, 0.f, 0.f, 0.f);
  float4 s2 = make_float4(0.f, 0.f, 0.f, 0.f);
  for (int r = blockIdx.x * 8 + rg; r < N; r += gridDim.x * 8) {
    float4 v = h[(size_t)r * 32 + q];
    s.x += v.x; s.y += v.y; s.z += v.z; s.w += v.w;
    s2.x += v.x * v.x; s2.y += v.y * v.y; s2.z += v.z * v.z; s2.w += v.w * v.w;
  }
  __shared__ float sm[256][8];
  sm[t][0] = s.x; sm[t][1] = s.y; sm[t][2] = s.z; sm[t][3] = s.w;
  sm[t][4] = s2.x; sm[t][5] = s2.y; sm[t][6] = s2.z; sm[t][7] = s2.w;
  __syncthreads();
  if (t < 32) {
    float a[8] = {0.f, 0.f, 0.f, 0.f, 0.f, 0.f, 0.f, 0.f};
    #pragma unroll
    for (int j = 0; j < 8; ++j)
      #pragma unroll
      for (int k = 0; k < 8; ++k) a[k] += sm[t + 32 * j][k];
    #pragma unroll
    for (int k = 0; k < 4; ++k) {
      atomicAdd(&stats[4 * t + k], a[k]);
      atomicAdd(&stats[128 + 4 * t + k], a[4 + k]);
    }
  }
}

__global__ void bn_scale(float* __restrict__ stats, const float* __restrict__ g,
                         const float* __restrict__ be, float invN) {
  int c = threadIdx.x;  // 128 threads
  float mean = stats[c] * invN;
  float var = stats[128 + c] * invN - mean * mean;
  float sc = g[c] * rsqrtf(var + BN_EPS);
  stats[256 + c] = sc;
  stats[384 + c] = be[c] - mean * sc;
}

// ---------------- layer-3 aggregation + bias + softmax (16 lanes/node, bf16 source) ----------------
__global__ __launch_bounds__(256) void agg40_softmax(const unsigned short* __restrict__ hb,
                                                     const float* __restrict__ dis,
                                                     const int* __restrict__ rowStart,
                                                     const int* __restrict__ counts,
                                                     const int* __restrict__ csrSrc,
                                                     const float* __restrict__ b3,
                                                     float* __restrict__ out, int N) {
  int l = threadIdx.x & 15;      // lanes 0..9 active (10*4 = 40 ch)
  int g = threadIdx.x >> 4;      // 16 nodes/block
  int i = blockIdx.x * 16 + g;
  if (i >= N) return;
  bool act = l < 10;
  float di = dis[i];
  float4 acc = make_float4(0.f, 0.f, 0.f, 0.f);
  if (act) {
    ushort4 sv = *(const ushort4*)&hb[(size_t)i * OUTC + l * 4];
    float w = di * di;
    acc.x = bf2f(sv.x) * w; acc.y = bf2f(sv.y) * w;
    acc.z = bf2f(sv.z) * w; acc.w = bf2f(sv.w) * w;
  }
  int s0 = rowStart[i];
  int cnt = counts[i];
  int e = 0;
  for (; e + 1 < cnt; e += 2) {
    int sA = csrSrc[s0 + e], sB = csrSrc[s0 + e + 1];
    float wA = dis[sA] * di, wB = dis[sB] * di;
    if (act) {
      ushort4 vA = *(const ushort4*)&hb[(size_t)sA * OUTC + l * 4];
      ushort4 vB = *(const ushort4*)&hb[(size_t)sB * OUTC + l * 4];
      acc.x += bf2f(vA.x) * wA; acc.y += bf2f(vA.y) * wA;
      acc.z += bf2f(vA.z) * wA; acc.w += bf2f(vA.w) * wA;
      acc.x += bf2f(vB.x) * wB; acc.y += bf2f(vB.y) * wB;
      acc.z += bf2f(vB.z) * wB; acc.w += bf2f(vB.w) * wB;
    }
  }
  if (e < cnt) {
    int sA = csrSrc[s0 + e];
    float wA = dis[sA] * di;
    if (act) {
      ushort4 vA = *(const ushort4*)&hb[(size_t)sA * OUTC + l * 4];
      acc.x += bf2f(vA.x) * wA; acc.y += bf2f(vA.y) * wA;
      acc.z += bf2f(vA.z) * wA; acc.w += bf2f(vA.w) * wA;
    }
  }
  if (act) {
    float4 b = ((const float4*)b3)[l];
    acc.x += b.x; acc.y += b.y; acc.z += b.z; acc.w += b.w;
  }
  float m = act ? fmaxf(fmaxf(acc.x, acc.y), fmaxf(acc.z, acc.w)) : -1e30f;
  #pragma unroll
  for (int off = 8; off; off >>= 1) m = fmaxf(m, __shfl_xor(m, off, 16));
  float4 ex = make_float4(0.f, 0.f, 0.f, 0.f);
  float lsum = 0.f;
  if (act) {
    ex.x = __expf(acc.x - m); ex.y = __expf(acc.y - m);
    ex.z = __expf(acc.z - m); ex.w = __expf(acc.w - m);
    lsum = ex.x + ex.y + ex.z + ex.w;
  }
  #pragma unroll
  for (int off = 8; off; off >>= 1) lsum += __shfl_xor(lsum, off, 16);
  if (act) {
    float inv = 1.0f / lsum;
    float4 o;
    o.x = ex.x * inv; o.y = ex.y * inv; o.z = ex.z * inv; o.w = ex.w * inv;
    *(float4*)&out[(size_t)i * OUTC + l * 4] = o;
  }
}

// ---------------- launcher ----------------
extern "C" void kernel_launch(void* const* d_in, const int* in_sizes, int n_in,
                              void* d_out, int out_size, void* d_ws, size_t ws_size,
                              hipStream_t stream) {
  const float* x   = (const float*)d_in[0];
  const int*   ei  = (const int*)d_in[1];
  const float* W1  = (const float*)d_in[2];
  const float* b1  = (const float*)d_in[3];
  const float* g1  = (const float*)d_in[4];
  const float* be1 = (const float*)d_in[5];
  const float* W2  = (const float*)d_in[6];
  const float* b2  = (const float*)d_in[7];
  const float* g2  = (const float*)d_in[8];
  const float* be2 = (const float*)d_in[9];
  const float* W3  = (const float*)d_in[10];
  const float* b3  = (const float*)d_in[11];

  const int N = in_sizes[0] / HIDC;
  const int E = in_sizes[1] / 2;
  const int NBUK = (N + 127) >> 7;
  const int* srcI = ei;
  const int* dstI = ei + E;

  float* outSoft = (float*)d_out;                       // [N,40]
  float* outH    = (float*)d_out + (size_t)N * OUTC;    // [N,128]; preBN temp, then final h

  char* ws = (char*)d_ws;
  size_t off = 0;
  auto alloc = [&](size_t bytes) -> char* {
    char* p = ws + off;
    off += (bytes + 255) & ~(size_t)255;
    return p;
  };
  unsigned short* bufAbf  = (unsigned short*)alloc((size_t)N * HIDC * 2);  // gemm out (bf16)
  unsigned short* buf40bf = (unsigned short*)alloc((size_t)N * OUTC * 2);  // gemm40 out (bf16)
  unsigned short* W1sz    = (unsigned short*)alloc(128 * 128 * 2);         // W1^T bf16 swz
  unsigned short* W2sz    = (unsigned short*)alloc(128 * 128 * 2);         // W2^T bf16 swz
  float*    dis         = (float*)alloc((size_t)N * 4);
  float*    stats       = (float*)alloc(1024 * 4);
  int*      bucketCount = (int*)alloc((size_t)MAXBUK * 4);
  int*      bucketStart = (int*)alloc((size_t)(MAXBUK + 1) * 4);
  int*      cursor      = (int*)alloc((size_t)MAXBUK * 4);
  int*      counts      = (int*)alloc((size_t)N * 4);
  int*      rowStart    = (int*)alloc((size_t)N * 4);
  unsigned* pairs       = (unsigned*)alloc((size_t)E * 4);
  int*      csrSrc      = (int*)alloc((size_t)E * 4);
  (void)ws_size; (void)n_in;

  hipMemsetAsync(bucketCount, 0, (size_t)MAXBUK * 4, stream);
  hipMemsetAsync(stats, 0, 1024 * 4, stream);

  // bucket-sorted CSR build (all writes coalesced) + W prep
  wprep<<<2, 256, 0, stream>>>(W1, W2, W1sz, W2sz);
  bin_hist<<<512, 256, 0, stream>>>(dstI, bucketCount, E, NBUK);
  scan_buckets<<<1, 512, 0, stream>>>(bucketCount, bucketStart, cursor, NBUK, E);
  bin_scatter<<<(E + TILE - 1) / TILE, 512, 0, stream>>>(srcI, dstI, cursor, pairs, E, NBUK);
  csr_from_pairs<<<NBUK, 256, 0, stream>>>(pairs, bucketStart, csrSrc, counts, rowStart,
                                           dis, N);

  const float invN = 1.0f / (float)N;

  // ---- Layer 1 ----
  gemm128m<false><<<(N + 63) / 64, 256, 0, stream>>>(x, W1sz, nullptr, nullptr, bufAbf, N);
  agg128<<<(N + 7) / 8, 256, 0, stream>>>(bufAbf, dis, rowStart, counts, csrSrc,
                                          b1, (float4*)outH, N);
  bn_stats<<<512, 256, 0, stream>>>((const float4*)outH, stats, N);
  bn_scale<<<1, 128, 0, stream>>>(stats, g1, be1, invN);

  // ---- Layer 2 (BN1+ReLU fused into gemm A-load) ----
  gemm128m<true><<<(N + 63) / 64, 256, 0, stream>>>(outH, W2sz, stats + 256, stats + 384,
                                                    bufAbf, N);
  agg128<<<(N + 7) / 8, 256, 0, stream>>>(bufAbf, dis, rowStart, counts, csrSrc,
                                          b2, (float4*)outH, N);
  bn_stats<<<512, 256, 0, stream>>>((const float4*)outH, stats + 512, N);
  bn_scale<<<1, 128, 0, stream>>>(stats + 512, g2, be2, invN);

  // ---- Layer 3 (BN2+ReLU fused into gemm40 load; writes post-BN h back to outH) ----
  gemm40<<<(N + 255) / 256, 256, 0, stream>>>(outH, W3, stats + 768, stats + 896,
                                              buf40bf, N);
  agg40_softmax<<<(N + 15) / 16, 256, 0, stream>>>(buf40bf, dis, rowStart, counts,
                                                   csrSrc, b3, outSoft, N);
}